// Round 1
// baseline (151.008 us; speedup 1.0000x reference)
//
#include <hip/hip_runtime.h>
#include <math.h>

// Problem constants (from reference)
#define BATCH 512
#define KA 8
#define KT 32
#define KX 512
#define DA 256
#define DS 768

#define AUTHOR_F4 (KA * DA / 4)   // 512 float4 per row
#define TITLE_F4  (KT * DS / 4)   // 6144 float4 per row
#define TEXT_F4   (KX * DS / 4)   // 98304 float4 per row
#define WA_F4 (DA / 4)            // 64
#define WS_F4 (DS / 4)            // 192

#define NT 512                    // threads per block (8 waves)
#define NWAVE (NT / 64)

// The softmax over a singleton axis in the reference makes all attention
// weights exactly 1.0, so each pool is a plain sum over K. The model
// collapses to 3 weighted reductions + a tiny per-row epilogue.
__global__ __launch_bounds__(NT) void fd_fused_kernel(
    const float* __restrict__ author,   // [B, KA, DA]
    const float* __restrict__ title,    // [B, KT, DS]
    const float* __restrict__ text,     // [B, KX, DS]
    const float* __restrict__ Wfa,      // [1, DA]
    const float* __restrict__ bfa,      // [1]
    const float* __restrict__ Wft,      // [1, DS]
    const float* __restrict__ bft,      // [1]
    const float* __restrict__ Wfx,      // [1, DS]
    const float* __restrict__ bfx,      // [1]
    const float* __restrict__ Wc,       // [2, 3] row-major
    const float* __restrict__ bc,       // [2]
    float* __restrict__ out)            // [B, 2]
{
    __shared__ float4 s_wfa[WA_F4];
    __shared__ float4 s_wft[WS_F4];
    __shared__ float4 s_wfx[WS_F4];
    __shared__ float s_red[3][NWAVE];

    const int t = threadIdx.x;
    const int b = blockIdx.x;

    // Stage scoring weights into LDS (7 KB)
    if (t < WA_F4) s_wfa[t] = ((const float4*)Wfa)[t];
    if (t < WS_F4) {
        s_wft[t] = ((const float4*)Wft)[t];
        s_wfx[t] = ((const float4*)Wfx)[t];
    }
    __syncthreads();

    const float4* tx = (const float4*)(text  + (size_t)b * (KX * DS));
    const float4* tt = (const float4*)(title + (size_t)b * (KT * DS));
    const float4* ta = (const float4*)(author + (size_t)b * (KA * DA));

    float accx = 0.f, acct = 0.f, acca = 0.f;

    // ---- text: 98304 float4, 192 iterations/thread, fully coalesced ----
    {
        int d4 = t % WS_F4;               // (flat f4 index) % 192 tracks d
        const int step = NT % WS_F4;      // 512 % 192 = 128
        #pragma unroll 4
        for (int i = t; i < TEXT_F4; i += NT) {
            float4 v = tx[i];
            float4 w = s_wfx[d4];
            accx += v.x * w.x + v.y * w.y + v.z * w.z + v.w * w.w;
            d4 += step; if (d4 >= WS_F4) d4 -= WS_F4;
        }
    }
    // ---- title: 6144 float4, 12 iterations/thread ----
    {
        int d4 = t % WS_F4;
        const int step = NT % WS_F4;
        #pragma unroll
        for (int i = t; i < TITLE_F4; i += NT) {
            float4 v = tt[i];
            float4 w = s_wft[d4];
            acct += v.x * w.x + v.y * w.y + v.z * w.z + v.w * w.w;
            d4 += step; if (d4 >= WS_F4) d4 -= WS_F4;
        }
    }
    // ---- author: 512 float4, exactly 1 per thread ----
    {
        float4 v = ta[t];
        float4 w = s_wfa[t % WA_F4];
        acca += v.x * w.x + v.y * w.y + v.z * w.z + v.w * w.w;
    }

    // ---- wave reduction (64-wide) ----
    #pragma unroll
    for (int off = 32; off > 0; off >>= 1) {
        accx += __shfl_down(accx, off, 64);
        acct += __shfl_down(acct, off, 64);
        acca += __shfl_down(acca, off, 64);
    }
    const int wave = t >> 6;
    const int lane = t & 63;
    if (lane == 0) {
        s_red[0][wave] = accx;
        s_red[1][wave] = acct;
        s_red[2][wave] = acca;
    }
    __syncthreads();

    // ---- epilogue on thread 0 ----
    if (t == 0) {
        float SX = 0.f, ST = 0.f, SA = 0.f;
        #pragma unroll
        for (int w = 0; w < NWAVE; ++w) {
            SX += s_red[0][w];
            ST += s_red[1][w];
            SA += s_red[2][w];
        }
        float va = SA + bfa[0];
        float vt = ST + bft[0];
        float vx = SX + bfx[0];
        float s0 = 1.f / (1.f + expf(-va));   // sigmoid(sa)
        float s1 = 1.f / (1.f + expf(-vt));   // sigmoid(st)
        float s2 = 1.f / (1.f + expf(-vx));   // sigmoid(sx)
        // logits = score @ Wc^T + bc ; Wc is [2,3] row-major
        float l0 = Wc[0] * s0 + Wc[1] * s1 + Wc[2] * s2 + bc[0];
        float l1 = Wc[3] * s0 + Wc[4] * s1 + Wc[5] * s2 + bc[1];
        float m = fmaxf(l0, l1);
        float e0 = expf(l0 - m), e1 = expf(l1 - m);
        float inv = 1.f / (e0 + e1);
        out[2 * b + 0] = e0 * inv;
        out[2 * b + 1] = e1 * inv;
    }
}

extern "C" void kernel_launch(void* const* d_in, const int* in_sizes, int n_in,
                              void* d_out, int out_size, void* d_ws, size_t ws_size,
                              hipStream_t stream) {
    // setup_inputs() order:
    //  0 author_emb [512,8,256]   1 title_emb [512,32,768]  2 text_emb [512,512,768]
    //  3 Wa 4 ba 5 ca 6 Wt 7 bt 8 ct 9 Wx 10 bx 11 cx      (dead: softmax over
    //    singleton axis makes attention weights identically 1)
    // 12 Wfa [1,256] 13 bfa [1] 14 Wft [1,768] 15 bft [1] 16 Wfx [1,768] 17 bfx [1]
    // 18 Wc [2,3] 19 bc [2]
    const float* author = (const float*)d_in[0];
    const float* title  = (const float*)d_in[1];
    const float* text   = (const float*)d_in[2];
    const float* Wfa = (const float*)d_in[12];
    const float* bfa = (const float*)d_in[13];
    const float* Wft = (const float*)d_in[14];
    const float* bft = (const float*)d_in[15];
    const float* Wfx = (const float*)d_in[16];
    const float* bfx = (const float*)d_in[17];
    const float* Wc  = (const float*)d_in[18];
    const float* bc  = (const float*)d_in[19];
    float* out = (float*)d_out;

    fd_fused_kernel<<<BATCH, NT, 0, stream>>>(
        author, title, text, Wfa, bfa, Wft, bft, Wfx, bfx, Wc, bc, out);
}

// Round 2
// 149.377 us; speedup vs baseline: 1.0109x; 1.0109x over previous
//
#include <hip/hip_runtime.h>
#include <math.h>

// Problem constants (from reference)
#define BATCH 512
#define KA 8
#define KT 32
#define KX 512
#define DA 256
#define DS 768

#define TITLE_F4  (KT * DS / 4)   // 6144 float4 per row
#define TEXT_F4   (KX * DS / 4)   // 98304 float4 per row
#define WA_F4 (DA / 4)            // 64
#define WS_F4 (DS / 4)            // 192

#define NT 1024                   // threads per block (16 waves)
#define NWAVE (NT / 64)
#define TEXT_ITER  (TEXT_F4 / NT)   // 96
#define TITLE_ITER (TITLE_F4 / NT)  // 6

// The softmax over a singleton axis in the reference makes all attention
// weights exactly 1.0, so each pool is a plain sum over K. The model
// collapses to 3 weighted reductions + a tiny per-row epilogue.
//
// Key trick: with thread-stride NT=1024 over a [*,768] row, the weight
// index (flat_f4 % 192) advances by 1024%192 = 64 per iteration -> period 3.
// Each thread needs only 3 weight float4s, held in registers. The hot loop
// is then pure global_load_dwordx4 + FMA: no LDS, no index math.
__global__ __launch_bounds__(NT, 8) void fd_fused_kernel(
    const float* __restrict__ author,   // [B, KA, DA]
    const float* __restrict__ title,    // [B, KT, DS]
    const float* __restrict__ text,     // [B, KX, DS]
    const float* __restrict__ Wfa,      // [1, DA]
    const float* __restrict__ bfa,      // [1]
    const float* __restrict__ Wft,      // [1, DS]
    const float* __restrict__ bft,      // [1]
    const float* __restrict__ Wfx,      // [1, DS]
    const float* __restrict__ bfx,      // [1]
    const float* __restrict__ Wc,       // [2, 3] row-major
    const float* __restrict__ bc,       // [2]
    float* __restrict__ out)            // [B, 2]
{
    __shared__ float s_red[3][NWAVE];

    const int t = threadIdx.x;
    const int b = blockIdx.x;

    const int d0 = t % WS_F4;              // weight f4 index at j=0
    const int d1 = (d0 + 64) % WS_F4;      // at j=1
    const int d2 = (d0 + 128) % WS_F4;     // at j=2

    const float4* wxp = (const float4*)Wfx;
    const float4* wtp = (const float4*)Wft;

    // ---- text: 98304 float4/row, 96 iters/thread, weights in registers ----
    float ax0 = 0.f, ax1 = 0.f, ax2 = 0.f;
    {
        const float4 w0 = wxp[d0], w1 = wxp[d1], w2 = wxp[d2];
        const float4* bx = (const float4*)(text + (size_t)b * (KX * DS)) + t;
        #pragma unroll 2
        for (int j = 0; j < TEXT_ITER; j += 3) {
            float4 v0 = bx[(j + 0) * NT];
            float4 v1 = bx[(j + 1) * NT];
            float4 v2 = bx[(j + 2) * NT];
            ax0 += v0.x * w0.x + v0.y * w0.y + v0.z * w0.z + v0.w * w0.w;
            ax1 += v1.x * w1.x + v1.y * w1.y + v1.z * w1.z + v1.w * w1.w;
            ax2 += v2.x * w2.x + v2.y * w2.y + v2.z * w2.z + v2.w * w2.w;
        }
    }
    float accx = ax0 + ax1 + ax2;

    // ---- title: 6144 float4/row, 6 iters/thread ----
    float acct;
    {
        const float4 w0 = wtp[d0], w1 = wtp[d1], w2 = wtp[d2];
        const float4* bt = (const float4*)(title + (size_t)b * (KT * DS)) + t;
        float at0 = 0.f, at1 = 0.f, at2 = 0.f;
        #pragma unroll
        for (int j = 0; j < TITLE_ITER; j += 3) {
            float4 v0 = bt[(j + 0) * NT];
            float4 v1 = bt[(j + 1) * NT];
            float4 v2 = bt[(j + 2) * NT];
            at0 += v0.x * w0.x + v0.y * w0.y + v0.z * w0.z + v0.w * w0.w;
            at1 += v1.x * w1.x + v1.y * w1.y + v1.z * w1.z + v1.w * w1.w;
            at2 += v2.x * w2.x + v2.y * w2.y + v2.z * w2.z + v2.w * w2.w;
        }
        acct = at0 + at1 + at2;
    }

    // ---- author: 512 float4/row, threads 0..511 take one each ----
    float acca = 0.f;
    if (t < KA * DA / 4) {
        float4 v = ((const float4*)(author + (size_t)b * (KA * DA)))[t];
        float4 w = ((const float4*)Wfa)[t % WA_F4];
        acca = v.x * w.x + v.y * w.y + v.z * w.z + v.w * w.w;
    }

    // ---- wave reduction (64-wide) ----
    #pragma unroll
    for (int off = 32; off > 0; off >>= 1) {
        accx += __shfl_down(accx, off, 64);
        acct += __shfl_down(acct, off, 64);
        acca += __shfl_down(acca, off, 64);
    }
    const int wave = t >> 6;
    const int lane = t & 63;
    if (lane == 0) {
        s_red[0][wave] = accx;
        s_red[1][wave] = acct;
        s_red[2][wave] = acca;
    }
    __syncthreads();

    // ---- epilogue on thread 0 ----
    if (t == 0) {
        float SX = 0.f, ST = 0.f, SA = 0.f;
        #pragma unroll
        for (int w = 0; w < NWAVE; ++w) {
            SX += s_red[0][w];
            ST += s_red[1][w];
            SA += s_red[2][w];
        }
        float va = SA + bfa[0];
        float vt = ST + bft[0];
        float vx = SX + bfx[0];
        float s0 = 1.f / (1.f + expf(-va));   // sigmoid(sa)
        float s1 = 1.f / (1.f + expf(-vt));   // sigmoid(st)
        float s2 = 1.f / (1.f + expf(-vx));   // sigmoid(sx)
        // logits = score @ Wc^T + bc ; Wc is [2,3] row-major
        float l0 = Wc[0] * s0 + Wc[1] * s1 + Wc[2] * s2 + bc[0];
        float l1 = Wc[3] * s0 + Wc[4] * s1 + Wc[5] * s2 + bc[1];
        float m = fmaxf(l0, l1);
        float e0 = expf(l0 - m), e1 = expf(l1 - m);
        float inv = 1.f / (e0 + e1);
        out[2 * b + 0] = e0 * inv;
        out[2 * b + 1] = e1 * inv;
    }
}

extern "C" void kernel_launch(void* const* d_in, const int* in_sizes, int n_in,
                              void* d_out, int out_size, void* d_ws, size_t ws_size,
                              hipStream_t stream) {
    // setup_inputs() order:
    //  0 author_emb [512,8,256]   1 title_emb [512,32,768]  2 text_emb [512,512,768]
    //  3..11 attention params (dead: softmax over singleton axis == ones)
    // 12 Wfa [1,256] 13 bfa [1] 14 Wft [1,768] 15 bft [1] 16 Wfx [1,768] 17 bfx [1]
    // 18 Wc [2,3] 19 bc [2]
    const float* author = (const float*)d_in[0];
    const float* title  = (const float*)d_in[1];
    const float* text   = (const float*)d_in[2];
    const float* Wfa = (const float*)d_in[12];
    const float* bfa = (const float*)d_in[13];
    const float* Wft = (const float*)d_in[14];
    const float* bft = (const float*)d_in[15];
    const float* Wfx = (const float*)d_in[16];
    const float* bfx = (const float*)d_in[17];
    const float* Wc  = (const float*)d_in[18];
    const float* bc  = (const float*)d_in[19];
    float* out = (float*)d_out;

    fd_fused_kernel<<<BATCH, NT, 0, stream>>>(
        author, title, text, Wfa, bfa, Wft, bft, Wfx, bfx, Wc, bc, out);
}

// Round 3
// 134.530 us; speedup vs baseline: 1.1225x; 1.1104x over previous
//
#include <hip/hip_runtime.h>
#include <math.h>

// Problem constants (from reference)
#define BATCH 512
#define KA 8
#define KT 32
#define KX 512
#define DA 256
#define DS 768

#define TITLE_F4  (KT * DS / 4)   // 6144 float4 per row
#define TEXT_F4   (KX * DS / 4)   // 98304 float4 per row
#define WA_F4 (DA / 4)            // 64
#define WS_F4 (DS / 4)            // 192

#define NT 1024                   // threads per block (16 waves)
#define NWAVE (NT / 64)
#define TEXT_ITER  (TEXT_F4 / NT)   // 96
#define TITLE_ITER (TITLE_F4 / NT)  // 6

typedef float f4v __attribute__((ext_vector_type(4)));

// The softmax over a singleton axis in the reference makes all attention
// weights exactly 1.0, so each pool is a plain sum over K. The model
// collapses to 3 weighted reductions + a tiny per-row epilogue.
//
// Streaming data has zero reuse -> nontemporal loads (global_load_dwordx4 nt)
// avoid allocating 860 MB/replay through the cache hierarchy.
// Weight index (flat_f4 % 192) has period 3 at stride 1024 -> weights live in
// 3 registers; hot loop is pure nt-load + FMA.
__global__ __launch_bounds__(NT, 8) void fd_fused_kernel(
    const float* __restrict__ author,   // [B, KA, DA]
    const float* __restrict__ title,    // [B, KT, DS]
    const float* __restrict__ text,     // [B, KX, DS]
    const float* __restrict__ Wfa,      // [1, DA]
    const float* __restrict__ bfa,      // [1]
    const float* __restrict__ Wft,      // [1, DS]
    const float* __restrict__ bft,      // [1]
    const float* __restrict__ Wfx,      // [1, DS]
    const float* __restrict__ bfx,      // [1]
    const float* __restrict__ Wc,       // [2, 3] row-major
    const float* __restrict__ bc,       // [2]
    float* __restrict__ out)            // [B, 2]
{
    __shared__ float s_red[3][NWAVE];

    const int t = threadIdx.x;
    const int b = blockIdx.x;

    const int d0 = t % WS_F4;              // weight f4 index at j=0
    const int d1 = (d0 + 64) % WS_F4;      // at j=1
    const int d2 = (d0 + 128) % WS_F4;     // at j=2

    const f4v* wxp = (const f4v*)Wfx;
    const f4v* wtp = (const f4v*)Wft;

    // ---- text: 98304 float4/row, 96 iters/thread, weights in registers ----
    f4v vx0 = {0.f, 0.f, 0.f, 0.f}, vx1 = vx0, vx2 = vx0;
    {
        const f4v w0 = wxp[d0], w1 = wxp[d1], w2 = wxp[d2];
        const f4v* bx = (const f4v*)(text + (size_t)b * (KX * DS)) + t;
        #pragma unroll 2
        for (int j = 0; j < TEXT_ITER; j += 3) {
            f4v v0 = __builtin_nontemporal_load(bx + (j + 0) * NT);
            f4v v1 = __builtin_nontemporal_load(bx + (j + 1) * NT);
            f4v v2 = __builtin_nontemporal_load(bx + (j + 2) * NT);
            vx0 += v0 * w0;
            vx1 += v1 * w1;
            vx2 += v2 * w2;
        }
    }
    f4v vxs = vx0 + vx1 + vx2;
    float accx = vxs[0] + vxs[1] + vxs[2] + vxs[3];

    // ---- title: 6144 float4/row, 6 iters/thread ----
    float acct;
    {
        const f4v w0 = wtp[d0], w1 = wtp[d1], w2 = wtp[d2];
        const f4v* bt = (const f4v*)(title + (size_t)b * (KT * DS)) + t;
        f4v vt0 = {0.f, 0.f, 0.f, 0.f}, vt1 = vt0, vt2 = vt0;
        #pragma unroll
        for (int j = 0; j < TITLE_ITER; j += 3) {
            f4v v0 = __builtin_nontemporal_load(bt + (j + 0) * NT);
            f4v v1 = __builtin_nontemporal_load(bt + (j + 1) * NT);
            f4v v2 = __builtin_nontemporal_load(bt + (j + 2) * NT);
            vt0 += v0 * w0;
            vt1 += v1 * w1;
            vt2 += v2 * w2;
        }
        f4v vts = vt0 + vt1 + vt2;
        acct = vts[0] + vts[1] + vts[2] + vts[3];
    }

    // ---- author: 512 float4/row, threads 0..511 take one each ----
    float acca = 0.f;
    if (t < KA * DA / 4) {
        f4v v = __builtin_nontemporal_load(
            (const f4v*)(author + (size_t)b * (KA * DA)) + t);
        f4v w = ((const f4v*)Wfa)[t % WA_F4];
        f4v p = v * w;
        acca = p[0] + p[1] + p[2] + p[3];
    }

    // ---- wave reduction (64-wide) ----
    #pragma unroll
    for (int off = 32; off > 0; off >>= 1) {
        accx += __shfl_down(accx, off, 64);
        acct += __shfl_down(acct, off, 64);
        acca += __shfl_down(acca, off, 64);
    }
    const int wave = t >> 6;
    const int lane = t & 63;
    if (lane == 0) {
        s_red[0][wave] = accx;
        s_red[1][wave] = acct;
        s_red[2][wave] = acca;
    }
    __syncthreads();

    // ---- epilogue on thread 0 ----
    if (t == 0) {
        float SX = 0.f, ST = 0.f, SA = 0.f;
        #pragma unroll
        for (int w = 0; w < NWAVE; ++w) {
            SX += s_red[0][w];
            ST += s_red[1][w];
            SA += s_red[2][w];
        }
        float va = SA + bfa[0];
        float vt = ST + bft[0];
        float vx = SX + bfx[0];
        float s0 = 1.f / (1.f + expf(-va));   // sigmoid(sa)
        float s1 = 1.f / (1.f + expf(-vt));   // sigmoid(st)
        float s2 = 1.f / (1.f + expf(-vx));   // sigmoid(sx)
        // logits = score @ Wc^T + bc ; Wc is [2,3] row-major
        float l0 = Wc[0] * s0 + Wc[1] * s1 + Wc[2] * s2 + bc[0];
        float l1 = Wc[3] * s0 + Wc[4] * s1 + Wc[5] * s2 + bc[1];
        float m = fmaxf(l0, l1);
        float e0 = expf(l0 - m), e1 = expf(l1 - m);
        float inv = 1.f / (e0 + e1);
        out[2 * b + 0] = e0 * inv;
        out[2 * b + 1] = e1 * inv;
    }
}

extern "C" void kernel_launch(void* const* d_in, const int* in_sizes, int n_in,
                              void* d_out, int out_size, void* d_ws, size_t ws_size,
                              hipStream_t stream) {
    // setup_inputs() order:
    //  0 author_emb [512,8,256]   1 title_emb [512,32,768]  2 text_emb [512,512,768]
    //  3..11 attention params (dead: softmax over singleton axis == ones)
    // 12 Wfa [1,256] 13 bfa [1] 14 Wft [1,768] 15 bft [1] 16 Wfx [1,768] 17 bfx [1]
    // 18 Wc [2,3] 19 bc [2]
    const float* author = (const float*)d_in[0];
    const float* title  = (const float*)d_in[1];
    const float* text   = (const float*)d_in[2];
    const float* Wfa = (const float*)d_in[12];
    const float* bfa = (const float*)d_in[13];
    const float* Wft = (const float*)d_in[14];
    const float* bft = (const float*)d_in[15];
    const float* Wfx = (const float*)d_in[16];
    const float* bfx = (const float*)d_in[17];
    const float* Wc  = (const float*)d_in[18];
    const float* bc  = (const float*)d_in[19];
    float* out = (float*)d_out;

    fd_fused_kernel<<<BATCH, NT, 0, stream>>>(
        author, title, text, Wfa, bfa, Wft, bft, Wfx, bfx, Wc, bc, out);
}